// Round 6
// baseline (340.255 us; speedup 1.0000x reference)
//
#include <hip/hip_runtime.h>
#include <math.h>

// ---------------------------------------------------------------------------
// GAT 3-layer pipeline. bf16 features + MFMA GEMMs, fused CSR edge-softmax.
//   el = h @ wl.T, wl[h,:] = al[h,:] @ Wsrc_h   (no fs materialization)
//   agg = (softmax-weighted sum of raw feats) @ Wsrc_h.T  (aggregate first)
// CSR built once upfront; per-dst gather computes max/exp/sum in-block.
// GEMM: global_load_lds(16B) staging, XOR seg-swizzle both sides.
// Dot kernels: register-hoisted wlr, 16 nodes/wave, range-split reduction
// (15 DS ops for ell-only nodes, 27 for ell+err nodes).
// ---------------------------------------------------------------------------

#define E0 375000
#define E1 90000
#define E2 10240
#define ETOT (E0 + E1 + E2)

static const int L_NS[3]   = {150000, 25000, 6000};
static const int L_ND[3]   = {25000, 6000, 1024};
static const int L_FIN[3]  = {256, 512, 512};
static const int L_FOUT[3] = {128, 128, 47};

typedef short bf8_t __attribute__((ext_vector_type(8)));
typedef float f32x4 __attribute__((ext_vector_type(4)));

__device__ __forceinline__ float lrelu(float v) { return v >= 0.f ? v : 0.2f * v; }
__device__ __forceinline__ unsigned short f2b(float f) {
  unsigned u = __float_as_uint(f);
  unsigned r = u + 0x7fffu + ((u >> 16) & 1u);
  return (unsigned short)(r >> 16);
}
__device__ __forceinline__ float b2f(unsigned v) {  // low 16 bits
  return __uint_as_float(v << 16);
}

// async global->LDS, 16B per lane; LDS dest = wave-uniform base + lane*16
__device__ __forceinline__ void gload16(const unsigned short* g, unsigned short* l) {
  __builtin_amdgcn_global_load_lds(
      (const __attribute__((address_space(1))) unsigned int*)g,
      (__attribute__((address_space(3))) unsigned int*)l, 16, 0, 0);
}

// 8-output cross-lane sum (ell+err): butterfly{8,16,32}x8, select, butterfly{1,2,4}.
__device__ __forceinline__ void reduce8_store(float v[8], int lane, int node, 
                                              float* __restrict__ ell,
                                              float* __restrict__ err) {
#pragma unroll
  for (int h = 0; h < 8; ++h) {
    v[h] += __shfl_xor(v[h], 8);
    v[h] += __shfl_xor(v[h], 16);
    v[h] += __shfl_xor(v[h], 32);
  }
  int sel = lane >> 3;
  float t01 = (sel & 1) ? v[1] : v[0];
  float t23 = (sel & 1) ? v[3] : v[2];
  float t45 = (sel & 1) ? v[5] : v[4];
  float t67 = (sel & 1) ? v[7] : v[6];
  float t03 = (sel & 2) ? t23 : t01;
  float t47 = (sel & 2) ? t67 : t45;
  float s   = (sel & 4) ? t47 : t03;
  s += __shfl_xor(s, 1);
  s += __shfl_xor(s, 2);
  s += __shfl_xor(s, 4);
  if ((lane & 7) == 0) {
    if (sel < 4) ell[(size_t)node * 4 + sel] = s;
    else err[(size_t)node * 4 + (sel - 4)] = s;
  }
}

// 4-output cross-lane sum (ell only): 15 DS ops.
__device__ __forceinline__ void reduce4_store(float v[8], int lane, int node,
                                              float* __restrict__ ell) {
#pragma unroll
  for (int h = 0; h < 4; ++h) {
    v[h] += __shfl_xor(v[h], 8);
    v[h] += __shfl_xor(v[h], 16);
    v[h] += __shfl_xor(v[h], 32);
  }
  int sel = (lane >> 3) & 3;
  float t01 = (sel & 1) ? v[1] : v[0];
  float t23 = (sel & 1) ? v[3] : v[2];
  float s   = (sel & 2) ? t23 : t01;
  s += __shfl_xor(s, 1);
  s += __shfl_xor(s, 2);
  s += __shfl_xor(s, 4);
  if ((lane & 7) == 0 && lane < 32) ell[(size_t)node * 4 + sel] = s;
}

// ---------------- prologue (one-shot, topology/weights only) ----------------

// fused: wlr build (first 10240 global threads) + bf16 weight conversion (grid-stride)
__global__ void k_prep(
    const float* __restrict__ Ws0, const float* __restrict__ Wd0,
    const float* __restrict__ al0, const float* __restrict__ ar0,
    const float* __restrict__ Ws1, const float* __restrict__ Wd1,
    const float* __restrict__ al1, const float* __restrict__ ar1,
    const float* __restrict__ Ws2, const float* __restrict__ Wd2,
    const float* __restrict__ al2, const float* __restrict__ ar2,
    float* __restrict__ wlr0, float* __restrict__ wlr1, float* __restrict__ wlr2,
    unsigned short* __restrict__ B0, unsigned short* __restrict__ B1,
    unsigned short* __restrict__ B2) {
  int gid = blockIdx.x * 256 + threadIdx.x;
  if (gid < 2048 + 8192) {
    int idx = gid;
    const float *Ws, *Wd, *al, *ar; float* wlr; int Fin, Fout;
    if (idx < 2048) { Ws = Ws0; Wd = Wd0; al = al0; ar = ar0; wlr = wlr0; Fin = 256; Fout = 128; }
    else if (idx < 2048 + 4096) { idx -= 2048; Ws = Ws1; Wd = Wd1; al = al1; ar = ar1; wlr = wlr1; Fin = 512; Fout = 128; }
    else { idx -= 2048 + 4096; Ws = Ws2; Wd = Wd2; al = al2; ar = ar2; wlr = wlr2; Fin = 512; Fout = 47; }
    int which = idx / (4 * Fin);
    int rem = idx - which * 4 * Fin;
    int h = rem / Fin, k = rem - h * Fin;
    const float* W = which ? Wd : Ws;
    const float* a = which ? ar : al;
    float acc = 0.f;
    for (int d = 0; d < Fout; ++d)
      acc += a[h * Fout + d] * W[(size_t)(h * Fout + d) * Fin + k];
    wlr[idx] = acc;
  }
  const int n0 = 512 * 256, n1 = 512 * 512, n2 = 188 * 512;
  for (int i = gid; i < n0 + n1 + n2; i += gridDim.x * 256) {
    if (i < n0) B0[i] = f2b(Ws0[i]);
    else if (i < n0 + n1) B1[i - n0] = f2b(Ws1[i - n0]);
    else B2[i - n0 - n1] = f2b(Ws2[i - n0 - n1]);
  }
}

__global__ void k_count_all(const int* __restrict__ d0, const int* __restrict__ d1,
                            const int* __restrict__ d2, int* __restrict__ c0,
                            int* __restrict__ c1, int* __restrict__ c2,
                            int* __restrict__ r) {
  int g = blockIdx.x * 256 + threadIdx.x;
  if (g >= ETOT) return;
  const int* d; int* c; int e;
  if (g < E0) { e = g; d = d0; c = c0; }
  else if (g < E0 + E1) { e = g - E0; d = d1; c = c1; }
  else { e = g - E0 - E1; d = d2; c = c2; }
  r[g] = atomicAdd(&c[d[e]], 1);
}

__global__ __launch_bounds__(1024) void k_scan3(
    const int* __restrict__ c0, int* __restrict__ r0, int n0,
    const int* __restrict__ c1, int* __restrict__ r1, int n1,
    const int* __restrict__ c2, int* __restrict__ r2, int n2) {
  const int* cnt; int* rowptr; int Nd;
  if (blockIdx.x == 0) { cnt = c0; rowptr = r0; Nd = n0; }
  else if (blockIdx.x == 1) { cnt = c1; rowptr = r1; Nd = n1; }
  else { cnt = c2; rowptr = r2; Nd = n2; }
  __shared__ int wsum[16];
  __shared__ int carry_s;
  int t = threadIdx.x, wid = t >> 6, lane = t & 63;
  if (t == 0) { carry_s = 0; rowptr[0] = 0; }
  __syncthreads();
  for (int base = 0; base < Nd; base += 4096) {
    int i0 = base + t * 4;
    int v0 = (i0 + 0 < Nd) ? cnt[i0 + 0] : 0;
    int v1 = (i0 + 1 < Nd) ? cnt[i0 + 1] : 0;
    int v2 = (i0 + 2 < Nd) ? cnt[i0 + 2] : 0;
    int v3 = (i0 + 3 < Nd) ? cnt[i0 + 3] : 0;
    int ts = v0 + v1 + v2 + v3;
    int s = ts;
    for (int off = 1; off < 64; off <<= 1) {
      int u = __shfl_up(s, off);
      if (lane >= off) s += u;
    }
    if (lane == 63) wsum[wid] = s;
    __syncthreads();
    int woff = carry_s;
    for (int w2 = 0; w2 < wid; ++w2) woff += wsum[w2];
    int excl = woff + s - ts;
    int p0 = excl + v0, p1 = p0 + v1, p2 = p1 + v2, p3 = p2 + v3;
    if (i0 + 0 < Nd) rowptr[i0 + 1] = p0;
    if (i0 + 1 < Nd) rowptr[i0 + 2] = p1;
    if (i0 + 2 < Nd) rowptr[i0 + 3] = p2;
    if (i0 + 3 < Nd) rowptr[i0 + 4] = p3;
    __syncthreads();
    if (t == 1023) carry_s = p3;
  }
}

__global__ void k_scatter_all(
    const int* __restrict__ s0, const int* __restrict__ d0, const int* __restrict__ rp0, int* __restrict__ cv0,
    const int* __restrict__ s1, const int* __restrict__ d1, const int* __restrict__ rp1, int* __restrict__ cv1,
    const int* __restrict__ s2, const int* __restrict__ d2, const int* __restrict__ rp2, int* __restrict__ cv2,
    const int* __restrict__ r) {
  int g = blockIdx.x * 256 + threadIdx.x;
  if (g >= ETOT) return;
  const int* s; const int* d; const int* rp; int* cv; int e;
  if (g < E0) { e = g; s = s0; d = d0; rp = rp0; cv = cv0; }
  else if (g < E0 + E1) { e = g - E0; s = s1; d = d1; rp = rp1; cv = cv1; }
  else { e = g - E0 - E1; s = s2; d = d2; rp = rp2; cv = cv2; }
  cv[rp[d[e]] + r[g]] = s[e];
}

// ---------------- per-layer feature kernels ----------------

// ell/err dot kernel. Block = 4 waves; each wave processes NPN nodes with
// wlr hoisted in registers. L0 additionally converts x to bf16.
template <int FIN, bool IS_L0>
__global__ __launch_bounds__(256) void k_dot(
    const void* __restrict__ Hv, const float* __restrict__ wlr,
    unsigned short* __restrict__ xbf, float* __restrict__ ell,
    float* __restrict__ err, int Ns, int Nd) {
  constexpr int NPN = 16;
  constexpr int CPL = FIN / 64;  // cols per lane: 4 (L0) or 8
  int w = threadIdx.x >> 6, lane = threadIdx.x & 63;
  int base = (blockIdx.x * 4 + w) * NPN;
  if (base >= Ns) return;
  float wl[4][CPL], wr[4][CPL];
#pragma unroll
  for (int h = 0; h < 4; ++h)
#pragma unroll
    for (int c = 0; c < CPL; ++c) {
      wl[h][c] = wlr[h * FIN + lane * CPL + c];
      wr[h][c] = wlr[4 * FIN + h * FIN + lane * CPL + c];
    }
  int nend = min(base + NPN, Ns);
  for (int node = base; node < nend; ++node) {
    float xv[CPL];
    if (IS_L0) {
      float4 a = *reinterpret_cast<const float4*>(
          (const float*)Hv + (size_t)node * FIN + lane * CPL);
      xv[0] = a.x; xv[1] = a.y; xv[2] = a.z; xv[3] = a.w;
      ushort4 ub;
      ub.x = f2b(a.x); ub.y = f2b(a.y); ub.z = f2b(a.z); ub.w = f2b(a.w);
      *reinterpret_cast<ushort4*>(xbf + (size_t)node * FIN + lane * CPL) = ub;
    } else {
      uint4 raw = *reinterpret_cast<const uint4*>(
          (const unsigned short*)Hv + (size_t)node * FIN + lane * CPL);
      xv[0] = b2f(raw.x & 0xffffu); xv[1] = b2f(raw.x >> 16);
      xv[2] = b2f(raw.y & 0xffffu); xv[3] = b2f(raw.y >> 16);
      if (CPL == 8) {
        xv[4] = b2f(raw.z & 0xffffu); xv[5] = b2f(raw.z >> 16);
        xv[6] = b2f(raw.w & 0xffffu); xv[7] = b2f(raw.w >> 16);
      }
    }
    float v[8];
    bool both = node < Nd;
#pragma unroll
    for (int h = 0; h < 4; ++h) {
      float a = 0.f;
#pragma unroll
      for (int c = 0; c < CPL; ++c) a = fmaf(wl[h][c], xv[c], a);
      v[h] = a;
    }
    if (both) {
#pragma unroll
      for (int h = 0; h < 4; ++h) {
        float a = 0.f;
#pragma unroll
        for (int c = 0; c < CPL; ++c) a = fmaf(wr[h][c], xv[c], a);
        v[4 + h] = a;
      }
      reduce8_store(v, lane, node, ell, err);
    } else {
      reduce4_store(v, lane, node, ell);
    }
  }
}

// fused per-dst softmax + weighted bf16 feature gather (block = one dst node).
// pass1: e-values -> LDS + block max; then lane-per-edge exp into LDS (weights);
// pass2: accumulate s and weighted features from LDS weights.
template <int FIN>
__global__ __launch_bounds__(FIN / 4) void k_gather_fused(
    const unsigned short* __restrict__ Hs, const float* __restrict__ ell,
    const float* __restrict__ err, const int* __restrict__ rowptr,
    const int* __restrict__ colv, unsigned short* __restrict__ Z) {
  constexpr int TB = FIN / 4;
  constexpr int NW = TB / 64;
  constexpr int CAP = 256;
  int n = blockIdx.x, t = threadIdx.x;
  int beg = rowptr[n], cnt = rowptr[n + 1] - beg;
  float4 er4 = *reinterpret_cast<const float4*>(err + (size_t)n * 4);
  __shared__ float4 esm[CAP];
  __shared__ int csm[CAP];
  __shared__ float4 wred[NW > 1 ? NW : 1];
  float m0 = -INFINITY, m1 = -INFINITY, m2 = -INFINITY, m3 = -INFINITY;
  for (int i = t; i < cnt; i += TB) {
    int c = colv[beg + i];
    float4 el4 = *reinterpret_cast<const float4*>(ell + (size_t)c * 4);
    float4 e4;
    e4.x = lrelu(el4.x + er4.x); e4.y = lrelu(el4.y + er4.y);
    e4.z = lrelu(el4.z + er4.z); e4.w = lrelu(el4.w + er4.w);
    if (i < CAP) { csm[i] = c; esm[i] = e4; }
    m0 = fmaxf(m0, e4.x); m1 = fmaxf(m1, e4.y);
    m2 = fmaxf(m2, e4.z); m3 = fmaxf(m3, e4.w);
  }
  for (int off = 32; off > 0; off >>= 1) {
    m0 = fmaxf(m0, __shfl_xor(m0, off));
    m1 = fmaxf(m1, __shfl_xor(m1, off));
    m2 = fmaxf(m2, __shfl_xor(m2, off));
    m3 = fmaxf(m3, __shfl_xor(m3, off));
  }
  if constexpr (NW > 1) {
    if ((t & 63) == 0) wred[t >> 6] = make_float4(m0, m1, m2, m3);
  }
  __syncthreads();  // esm/csm (+wred) visible
  if constexpr (NW > 1) {
    float4 wa = wred[0], wb = wred[1];
    m0 = fmaxf(wa.x, wb.x); m1 = fmaxf(wa.y, wb.y);
    m2 = fmaxf(wa.z, wb.z); m3 = fmaxf(wa.w, wb.w);
  }
  float s0 = 0.f, s1 = 0.f, s2 = 0.f, s3 = 0.f;
  float acc[4][4] = {};

#define GAT_ACC(w4, xr)                                                        \
  {                                                                            \
    float w0 = w4.x, w1 = w4.y, w2 = w4.z, w3 = w4.w;                          \
    s0 += w0; s1 += w1; s2 += w2; s3 += w3;                                    \
    float x0 = b2f(xr.x), x1 = b2f(xr.y), x2 = b2f(xr.z), x3 = b2f(xr.w);      \
    acc[0][0] = fmaf(w0, x0, acc[0][0]); acc[0][1] = fmaf(w0, x1, acc[0][1]);  \
    acc[0][2] = fmaf(w0, x2, acc[0][2]); acc[0][3] = fmaf(w0, x3, acc[0][3]);  \
    acc[1][0] = fmaf(w1, x0, acc[1][0]); acc[1][1] = fmaf(w1, x1, acc[1][1]);  \
    acc[1][2] = fmaf(w1, x2, acc[1][2]); acc[1][3] = fmaf(w1, x3, acc[1][3]);  \
    acc[2][0] = fmaf(w2, x0, acc[2][0]); acc[2][1] = fmaf(w2, x1, acc[2][1]);  \
    acc[2][2] = fmaf(w2, x2, acc[2][2]); acc[2][3] = fmaf(w2, x3, acc[2][3]);  \
    acc[3][0] = fmaf(w3, x0, acc[3][0]); acc[3][1] = fmaf(w3, x1, acc[3][1]);  \
    acc[3][2] = fmaf(w3, x2, acc[3][2]); acc[3][3] = fmaf(w3, x3, acc[3][3]);  \
  }

  if (cnt <= CAP) {
    // lane-per-edge exp: e -> weight, once per edge instead of per thread
    for (int i = t; i < cnt; i += TB) {
      float4 e = esm[i];
      esm[i] = make_float4(__expf(e.x - m0), __expf(e.y - m1),
                           __expf(e.z - m2), __expf(e.w - m3));
    }
    __syncthreads();
    int j = 0;
    for (; j + 2 <= cnt; j += 2) {
      float4 wa = esm[j], wb = esm[j + 1];
      int ca = csm[j], cb = csm[j + 1];
      ushort4 xa = *reinterpret_cast<const ushort4*>(Hs + (size_t)ca * FIN + t * 4);
      ushort4 xb = *reinterpret_cast<const ushort4*>(Hs + (size_t)cb * FIN + t * 4);
      GAT_ACC(wa, xa);
      GAT_ACC(wb, xb);
    }
    if (j < cnt) {
      float4 wa = esm[j];
      ushort4 xa = *reinterpret_cast<const ushort4*>(Hs + (size_t)csm[j] * FIN + t * 4);
      GAT_ACC(wa, xa);
    }
  } else {
    for (int j = 0; j < cnt; ++j) {
      int c = colv[beg + j];
      float4 el4 = *reinterpret_cast<const float4*>(ell + (size_t)c * 4);
      float4 w4;
      w4.x = __expf(lrelu(el4.x + er4.x) - m0);
      w4.y = __expf(lrelu(el4.y + er4.y) - m1);
      w4.z = __expf(lrelu(el4.z + er4.z) - m2);
      w4.w = __expf(lrelu(el4.w + er4.w) - m3);
      ushort4 xa = *reinterpret_cast<const ushort4*>(Hs + (size_t)c * FIN + t * 4);
      GAT_ACC(w4, xa);
    }
  }
#undef GAT_ACC
  float inv[4];
  inv[0] = 1.f / fmaxf(s0, 1e-9f); inv[1] = 1.f / fmaxf(s1, 1e-9f);
  inv[2] = 1.f / fmaxf(s2, 1e-9f); inv[3] = 1.f / fmaxf(s3, 1e-9f);
#pragma unroll
  for (int h = 0; h < 4; ++h) {
    ushort4 o;
    o.x = f2b(acc[h][0] * inv[h]); o.y = f2b(acc[h][1] * inv[h]);
    o.z = f2b(acc[h][2] * inv[h]); o.w = f2b(acc[h][3] * inv[h]);
    *reinterpret_cast<ushort4*>(Z + (size_t)n * 4 * FIN + h * FIN + t * 4) = o;
  }
}

// bf16 MFMA GEMM, per-head: out[m, h*N+n] = (Z_h @ W_h^T)[m,n] + bias  (opt ELU)
// 128xBN tile, BK=64, 256 thr (4 waves), global_load_lds staging, XOR swizzle.
template <int BN, bool ACT, bool OUTBF>
__global__ __launch_bounds__(256) void k_gemm_mfma(
    const unsigned short* __restrict__ Zb, const unsigned short* __restrict__ Wb,
    const float* __restrict__ bias, void* __restrict__ outv,
    int M, int N, int K) {
  constexpr int FN = BN / 16;
  constexpr int AI = 4;        // A gload instrs per thread (16 chunks / 4 waves)
  constexpr int BI = BN / 32;  // B gload instrs per thread
  int h = blockIdx.z;
  __shared__ unsigned short As[128 * 64];  // linear; 16KB
  __shared__ unsigned short Bs[BN * 64];
  const int tid = threadIdx.x;
  const int w = tid >> 6, lane = tid & 63;
  const int bm = blockIdx.x * 128, bn = blockIdx.y * BN;
  const int lda = 4 * K;
  const unsigned short* Ag = Zb + (size_t)h * K;
  const unsigned short* Bg = Wb + (size_t)h * N * K;
  const int lrow = lane >> 3;           // row within 8-row chunk
  const int gseg = (lane & 7) ^ lrow;   // swizzled source 16B-seg (involution)
  f32x4 acc[2][FN];
#pragma unroll
  for (int i = 0; i < 2; ++i)
#pragma unroll
    for (int j = 0; j < FN; ++j) acc[i][j] = (f32x4){0.f, 0.f, 0.f, 0.f};

  for (int k0 = 0; k0 < K; k0 += 64) {
    __syncthreads();  // prev iter's ds_reads done before DMA overwrite
#pragma unroll
    for (int i = 0; i < AI; ++i) {
      int ch = w * AI + i;            // 0..15
      int row = ch * 8 + lrow;        // 0..127
      int gm = bm + row; gm = gm < M ? gm : M - 1;
      gload16(Ag + (size_t)gm * lda + k0 + gseg * 8, As + ch * 512);
    }
#pragma unroll
    for (int i = 0; i < BI; ++i) {
      int ch = w * BI + i;
      int row = ch * 8 + lrow;        // 0..BN-1
      int gn = bn + row; gn = gn < N ? gn : N - 1;
      gload16(Bg + (size_t)gn * K + k0 + gseg * 8, Bs + ch * 512);
    }
    __syncthreads();  // compiler drains vmcnt(0) before barrier
    const int ra = w * 32 + (lane & 15);
#pragma unroll
    for (int ks = 0; ks < 2; ++ks) {
      int cs = ((((ks << 2) + (lane >> 4)) ^ (lane & 7)) << 3);  // swizzled k-offset (shorts)
      bf8_t a0 = *reinterpret_cast<const bf8_t*>(As + ra * 64 + cs);
      bf8_t a1 = *reinterpret_cast<const bf8_t*>(As + (ra + 16) * 64 + cs);
#pragma unroll
      for (int fn = 0; fn < FN; ++fn) {
        bf8_t bf = *reinterpret_cast<const bf8_t*>(Bs + (fn * 16 + (lane & 15)) * 64 + cs);
        acc[0][fn] = __builtin_amdgcn_mfma_f32_16x16x32_bf16(a0, bf, acc[0][fn], 0, 0, 0);
        acc[1][fn] = __builtin_amdgcn_mfma_f32_16x16x32_bf16(a1, bf, acc[1][fn], 0, 0, 0);
      }
    }
  }
  int ldo = 4 * N;
#pragma unroll
  for (int fm = 0; fm < 2; ++fm) {
#pragma unroll
    for (int fn = 0; fn < FN; ++fn) {
      int colb = bn + fn * 16 + (lane & 15);
      if (colb >= N) continue;
      float bv = bias[h * N + colb];
#pragma unroll
      for (int j = 0; j < 4; ++j) {
        int rowb = bm + w * 32 + fm * 16 + (lane >> 4) * 4 + j;
        if (rowb >= M) continue;
        float v = acc[fm][fn][j] + bv;
        if (ACT) v = v > 0.f ? v : (__expf(v) - 1.f);
        size_t off = (size_t)rowb * ldo + (size_t)h * N + colb;
        if (OUTBF) ((unsigned short*)outv)[off] = f2b(v);
        else ((float*)outv)[off] = v;
      }
    }
  }
}

// mean over 4 heads (C=47) + log_softmax; one wave per node
__global__ __launch_bounds__(256) void k_mean_lsm(const float* __restrict__ rst2,
                                                  float* __restrict__ out, int Nd) {
  int node = blockIdx.x * 4 + (threadIdx.x >> 6);
  int lane = threadIdx.x & 63;
  if (node >= Nd) return;
  const float* r = rst2 + (size_t)node * 188;
  float vv = 0.f;
  if (lane < 47)
    vv = 0.25f * (r[lane] + r[47 + lane] + r[94 + lane] + r[141 + lane]);
  float m = (lane < 47) ? vv : -INFINITY;
  for (int off = 32; off > 0; off >>= 1) m = fmaxf(m, __shfl_xor(m, off));
  float ex = (lane < 47) ? __expf(vv - m) : 0.f;
  float ss = ex;
  for (int off = 32; off > 0; off >>= 1) ss += __shfl_xor(ss, off);
  if (lane < 47) out[(size_t)node * 47 + lane] = vv - m - logf(ss);
}

extern "C" void kernel_launch(void* const* d_in, const int* in_sizes, int n_in,
                              void* d_out, int out_size, void* d_ws, size_t ws_size,
                              hipStream_t stream) {
  (void)in_sizes; (void)n_in; (void)out_size; (void)ws_size;
  const float* x = (const float*)d_in[0];
  const int* srcs[3] = {(const int*)d_in[1], (const int*)d_in[3], (const int*)d_in[5]};
  const int* dsts[3] = {(const int*)d_in[2], (const int*)d_in[4], (const int*)d_in[6]};
  const float* Wsrc[3] = {(const float*)d_in[7], (const float*)d_in[12], (const float*)d_in[17]};
  const float* Wdst[3] = {(const float*)d_in[8], (const float*)d_in[13], (const float*)d_in[18]};
  const float* al[3]   = {(const float*)d_in[9], (const float*)d_in[14], (const float*)d_in[19]};
  const float* ar[3]   = {(const float*)d_in[10], (const float*)d_in[15], (const float*)d_in[20]};
  const float* bb[3]   = {(const float*)d_in[11], (const float*)d_in[16], (const float*)d_in[21]};

  char* p = (char*)d_ws;
  auto alloc = [&](size_t bytes) -> void* {
    void* r = (void*)p;
    p += (bytes + 255) & ~(size_t)255;
    return r;
  };
  unsigned short* xbf = (unsigned short*)alloc((size_t)150000 * 256 * 2);
  unsigned short* zbf = (unsigned short*)alloc((size_t)25000 * 1024 * 2);
  unsigned short* h1  = (unsigned short*)alloc((size_t)25000 * 512 * 2);
  unsigned short* h2  = (unsigned short*)alloc((size_t)6000 * 512 * 2);
  float* rst2   = (float*)alloc((size_t)1024 * 188 * 4);
  unsigned short* Wb0 = (unsigned short*)alloc((size_t)512 * 256 * 2);
  unsigned short* Wb1 = (unsigned short*)alloc((size_t)512 * 512 * 2);
  unsigned short* Wb2 = (unsigned short*)alloc((size_t)188 * 512 * 2);
  float* ell    = (float*)alloc((size_t)150000 * 4 * 4);
  float* err    = (float*)alloc((size_t)25000 * 4 * 4);
  int* cntAll   = (int*)alloc((size_t)(25000 + 6000 + 1024) * 4);
  int* rp0      = (int*)alloc((size_t)25001 * 4);
  int* rp1      = (int*)alloc((size_t)6001 * 4);
  int* rp2      = (int*)alloc((size_t)1025 * 4);
  int* r_all    = (int*)alloc((size_t)ETOT * 4);
  int* cv0      = (int*)alloc((size_t)E0 * 4);
  int* cv1      = (int*)alloc((size_t)E1 * 4);
  int* cv2      = (int*)alloc((size_t)E2 * 4);
  float* wlr0   = (float*)alloc((size_t)8 * 256 * 4);
  float* wlr1   = (float*)alloc((size_t)8 * 512 * 4);
  float* wlr2   = (float*)alloc((size_t)8 * 512 * 4);

  int* cnt0 = cntAll, *cnt1 = cntAll + 25000, *cnt2 = cntAll + 31000;

  // ---- one-shot prologue: CSR + weight prep
  hipMemsetAsync(cntAll, 0, (size_t)(25000 + 6000 + 1024) * 4, stream);
  k_count_all<<<(ETOT + 255) / 256, 256, 0, stream>>>(
      dsts[0], dsts[1], dsts[2], cnt0, cnt1, cnt2, r_all);
  k_scan3<<<3, 1024, 0, stream>>>(cnt0, rp0, 25000, cnt1, rp1, 6000, cnt2, rp2, 1024);
  k_scatter_all<<<(ETOT + 255) / 256, 256, 0, stream>>>(
      srcs[0], dsts[0], rp0, cv0, srcs[1], dsts[1], rp1, cv1,
      srcs[2], dsts[2], rp2, cv2, r_all);
  k_prep<<<512, 256, 0, stream>>>(
      Wsrc[0], Wdst[0], al[0], ar[0], Wsrc[1], Wdst[1], al[1], ar[1],
      Wsrc[2], Wdst[2], al[2], ar[2], wlr0, wlr1, wlr2, Wb0, Wb1, Wb2);

  const unsigned short* Hbf[3] = {xbf, h1, h2};
  const unsigned short* Wbf[3] = {Wb0, Wb1, Wb2};
  const float* wlrs[3] = {wlr0, wlr1, wlr2};
  const int* rps[3] = {rp0, rp1, rp2};
  const int* cvs[3] = {cv0, cv1, cv2};

  for (int l = 0; l < 3; ++l) {
    int Ns = L_NS[l], Nd = L_ND[l], Fin = L_FIN[l], Fout = L_FOUT[l];
    if (l == 0)
      k_dot<256, true><<<(Ns + 63) / 64, 256, 0, stream>>>(
          x, wlrs[l], xbf, ell, err, Ns, Nd);
    else
      k_dot<512, false><<<(Ns + 63) / 64, 256, 0, stream>>>(
          Hbf[l], wlrs[l], nullptr, ell, err, Ns, Nd);
    if (Fin == 256)
      k_gather_fused<256><<<Nd, 64, 0, stream>>>(Hbf[l], ell, err, rps[l], cvs[l], zbf);
    else
      k_gather_fused<512><<<Nd, 128, 0, stream>>>(Hbf[l], ell, err, rps[l], cvs[l], zbf);
    dim3 g((Nd + 127) / 128, 1, 4);
    if (l == 0)
      k_gemm_mfma<128, true, true><<<g, 256, 0, stream>>>(zbf, Wbf[l], bb[l], h1, Nd, Fout, Fin);
    else if (l == 1)
      k_gemm_mfma<128, true, true><<<g, 256, 0, stream>>>(zbf, Wbf[l], bb[l], h2, Nd, Fout, Fin);
    else
      k_gemm_mfma<64, false, false><<<g, 256, 0, stream>>>(zbf, Wbf[l], bb[l], rst2, Nd, Fout, Fin);
  }
  k_mean_lsm<<<(1024 + 3) / 4, 256, 0, stream>>>(rst2, (float*)d_out, 1024);
}